// Round 3
// baseline (134.492 us; speedup 1.0000x reference)
//
#include <hip/hip_runtime.h>
#include <math.h>

constexpr int NSEG = 128;
constexpr int P    = 512;
constexpr int D    = 64;
constexpr int KT   = 15;
constexpr int NCLS = 8;

// ws layout: [0..127] int per-segment arrival counters; [128] int gcount;
// [129] float gaccum; dist array (NSEG*P floats) at byte offset 1024.
// Only the first 1024 bytes need zeroing (one tiny memset).

__global__ __launch_bounds__(256) void lmnn_fused(
    const float* __restrict__ center,   // (NSEG, D)
    const float* __restrict__ outputs,  // (NSEG, P, D)
    const int*   __restrict__ labels,   // (NSEG, P)
    float* __restrict__ out,            // scalar
    int*   __restrict__ counters,       // NSEG
    int*   __restrict__ gcount,         // 1
    float* __restrict__ gaccum,         // 1
    float* __restrict__ dist)           // (NSEG, P)
{
    const int seg     = blockIdx.x >> 2;
    const int quarter = blockIdx.x & 3;
    const int t   = threadIdx.x;
    const int sub = t & 15;    // dim chunk (4 floats)
    const int pg  = t >> 4;    // point within group of 16

    // ---- phase A: dist for this block's 128 points (fully coalesced) ----
    const float4* c4 = reinterpret_cast<const float4*>(center);
    const float4  cf = c4[seg * 16 + sub];
    const float4* o4 = reinterpret_cast<const float4*>(outputs);
    const int pt_base = quarter * 128;

    #pragma unroll
    for (int it = 0; it < 8; ++it) {
        const int pt = pt_base + it * 16 + pg;
        float4 v = o4[((size_t)seg * P + pt) * 16 + sub];
        float dx = v.x - cf.x;
        float dy = v.y - cf.y;
        float dz = v.z - cf.z;
        float dw = v.w - cf.w;
        float acc = dx * dx + dy * dy + dz * dz + dw * dw;
        acc += __shfl_xor(acc, 1);
        acc += __shfl_xor(acc, 2);
        acc += __shfl_xor(acc, 4);
        acc += __shfl_xor(acc, 8);
        if (sub == 0) dist[seg * P + pt] = acc;
    }

    // ---- arrival protocol: 4th block of each segment does the combine ----
    __threadfence();            // release: each thread's dist stores
    __syncthreads();            // all threads of this block have fenced
    __shared__ int s_old;
    if (t == 0) s_old = atomicAdd(&counters[seg], 1);
    __syncthreads();
    if (s_old != 3) return;
    __threadfence();            // acquire: see sibling blocks' dist stores

    // ---- combine for this segment (256 threads = 4 waves) ----
    __shared__ float s_dist[P];
    __shared__ int   s_lab[P];
    __shared__ float s_S[NCLS];
    __shared__ float s_M[NCLS];
    __shared__ int   s_cnt[NCLS];
    __shared__ float s_hb[NCLS];
    __shared__ float s_dc[NCLS];
    __shared__ float s_margin;
    __shared__ float s_pull;
    __shared__ float s_wsum[4];

    s_lab[t]        = labels[seg * P + t];
    s_lab[t + 256]  = labels[seg * P + t + 256];
    s_dist[t]       = dist[seg * P + t];
    s_dist[t + 256] = dist[seg * P + t + 256];
    __syncthreads();

    const int lane = t & 63;
    const int wave = t >> 6;

    // per-class first-15 stats; wave w owns classes w and w+4
    for (int ci = 0; ci < 2; ++ci) {
        const int c = wave + ci * 4;
        float S = 0.0f;
        float M = -INFINITY;
        int taken = 0;
        int total = 0;
        for (int j = 0; j < 8; ++j) {
            const int pos = j * 64 + lane;
            const bool pred = (s_lab[pos] == c);
            const unsigned long long mask = __ballot(pred);
            const int cnt  = __popcll(mask);
            const int rank = __popcll(mask & ((1ull << lane) - 1ull));
            const bool sel = pred && (taken + rank < KT);
            float vs = sel ? s_dist[pos] : 0.0f;
            float vm = sel ? s_dist[pos] : -INFINITY;
            #pragma unroll
            for (int m = 1; m < 64; m <<= 1) {
                vs += __shfl_xor(vs, m);
                vm = fmaxf(vm, __shfl_xor(vm, m));
            }
            S += vs;
            M = fmaxf(M, vm);
            total += cnt;
            taken += cnt;
            if (taken > KT) taken = KT;
        }
        // Rare: fewer than 15 same-class members -> top_k fills with
        // lowest-index different-class entries (all tied at -inf).
        if (total < KT) {
            const int need = KT - total;
            int t2 = 0;
            for (int j = 0; j < 8 && t2 < need; ++j) {
                const int pos = j * 64 + lane;
                const bool pred = (s_lab[pos] != c);
                const unsigned long long mask = __ballot(pred);
                const int cnt  = __popcll(mask);
                const int rank = __popcll(mask & ((1ull << lane) - 1ull));
                const bool sel = pred && (t2 + rank < need);
                float vs = sel ? s_dist[pos] : 0.0f;
                float vm = sel ? s_dist[pos] : -INFINITY;
                #pragma unroll
                for (int m = 1; m < 64; m <<= 1) {
                    vs += __shfl_xor(vs, m);
                    vm = fmaxf(vm, __shfl_xor(vm, m));
                }
                S += vs;
                M = fmaxf(M, vm);
                t2 += cnt;
                if (t2 > need) t2 = need;
            }
        }
        if (lane == 0) {
            s_S[c]   = S;
            s_M[c]   = M;
            s_cnt[c] = total;
        }
    }
    __syncthreads();

    if (t == 0) {
        float margin = -INFINITY;
        float pull = 0.0f;
        for (int c = 0; c < NCLS; ++c) {
            if (s_cnt[c] > 0) margin = fmaxf(margin, s_M[c]);
            pull += (float)s_cnt[c] * s_S[c];
            s_hb[c] = 1.0f + s_M[c];
            s_dc[c] = (float)(P - s_cnt[c]);
        }
        s_margin = 1.0f + margin;
        s_pull = pull;
    }
    __syncthreads();

    // push term: 2 points per thread
    {
        float v = 0.0f;
        #pragma unroll
        for (int k = 0; k < 2; ++k) {
            const int pos = t + k * 256;
            const float dv = s_dist[pos];
            const int   c  = s_lab[pos];
            const float h  = fmaxf(s_hb[c] - dv, 0.0f);
            v += (dv < s_margin) ? s_dc[c] * h : 0.0f;
        }
        #pragma unroll
        for (int m = 1; m < 64; m <<= 1) v += __shfl_xor(v, m);
        if (lane == 0) s_wsum[wave] = v;
    }
    __syncthreads();

    if (t == 0) {
        float tt = s_pull + s_wsum[0] + s_wsum[1] + s_wsum[2] + s_wsum[3];
        atomicAdd(gaccum, tt);
        __threadfence();
        const int o2 = atomicAdd(gcount, 1);
        if (o2 == NSEG - 1) {
            __threadfence();
            const float tot = atomicAdd(gaccum, 0.0f);  // coherent read
            out[0] = tot * (1.0f / ((float)NSEG * (float)P));
        }
    }
}

extern "C" void kernel_launch(void* const* d_in, const int* in_sizes, int n_in,
                              void* d_out, int out_size, void* d_ws, size_t ws_size,
                              hipStream_t stream) {
    const float* center  = (const float*)d_in[0];  // (128, 64)
    const float* outputs = (const float*)d_in[1];  // (128, 512, 64)
    const int*   labels  = (const int*)d_in[2];    // (128, 512)
    float* out = (float*)d_out;

    int*   counters = (int*)d_ws;                       // [0..127]
    int*   gcount   = counters + NSEG;                  // [128]
    float* gaccum   = (float*)(counters + NSEG + 1);    // [129]
    float* dist     = (float*)((char*)d_ws + 1024);     // 256 KB

    // zero only the control block (counters + gcount + gaccum)
    hipMemsetAsync(d_ws, 0, 1024, stream);
    lmnn_fused<<<dim3(NSEG * 4), dim3(256), 0, stream>>>(
        center, outputs, labels, out, counters, gcount, gaccum, dist);
}

// Round 4
// 75.391 us; speedup vs baseline: 1.7839x; 1.7839x over previous
//
#include <hip/hip_runtime.h>
#include <math.h>

constexpr int NSEG = 128;
constexpr int P    = 512;
constexpr int D    = 64;
constexpr int KT   = 15;
constexpr int NCLS = 8;

// ---------------- Kernel A: dist_c[seg][pt] = ||outputs - center||^2 -------
// 512 blocks x 256 threads: 4 blocks per segment, each handles 128 points.
// 16 lanes per point (float4 per lane) -> fully-coalesced 4 KB per iteration.
// Block 0 also zeroes out[0]; kernel-boundary release/acquire makes it
// visible to combine_kernel's atomicAdds (no fences, no extra dispatch).
__global__ __launch_bounds__(256) void dist_kernel(
    const float* __restrict__ center,   // (NSEG, D)
    const float* __restrict__ outputs,  // (NSEG, P, D)
    float* __restrict__ dist,           // (NSEG, P) in d_ws
    float* __restrict__ out)            // scalar, zeroed here
{
    if (blockIdx.x == 0 && threadIdx.x == 0) out[0] = 0.0f;

    const int seg     = blockIdx.x >> 2;
    const int quarter = blockIdx.x & 3;
    const int t   = threadIdx.x;
    const int sub = t & 15;    // dim chunk (4 floats)
    const int pg  = t >> 4;    // point within group of 16

    const float4* c4 = reinterpret_cast<const float4*>(center);
    const float4  cf = c4[seg * 16 + sub];

    const float4* o4 = reinterpret_cast<const float4*>(outputs);
    const int pt_base = quarter * 128;

    #pragma unroll
    for (int it = 0; it < 8; ++it) {
        const int pt = pt_base + it * 16 + pg;
        float4 v = o4[((size_t)seg * P + pt) * 16 + sub];
        float dx = v.x - cf.x;
        float dy = v.y - cf.y;
        float dz = v.z - cf.z;
        float dw = v.w - cf.w;
        float acc = dx * dx + dy * dy + dz * dz + dw * dw;
        acc += __shfl_xor(acc, 1);
        acc += __shfl_xor(acc, 2);
        acc += __shfl_xor(acc, 4);
        acc += __shfl_xor(acc, 8);
        if (sub == 0) dist[seg * P + pt] = acc;
    }
}

// ---------------- Kernel B: phases 2-4 on the 256 KB dist array ------------
__global__ __launch_bounds__(512, 1) void combine_kernel(
    const float* __restrict__ dist,     // (NSEG, P) in d_ws
    const int*   __restrict__ labels,   // (NSEG, P)
    float* __restrict__ out)            // scalar (pre-zeroed by dist_kernel)
{
    __shared__ float s_dist[P];
    __shared__ int   s_lab[P];
    __shared__ float s_S[NCLS];
    __shared__ float s_M[NCLS];
    __shared__ int   s_cnt[NCLS];
    __shared__ float s_hb[NCLS];   // 1 + M[c]
    __shared__ float s_dc[NCLS];   // P - cnt[c]
    __shared__ float s_margin;
    __shared__ float s_pull;
    __shared__ float s_wsum[8];

    const int seg  = blockIdx.x;
    const int tid  = threadIdx.x;
    const int lane = tid & 63;
    const int wave = tid >> 6;

    s_lab[tid]  = labels[seg * P + tid];
    s_dist[tid] = dist[seg * P + tid];
    __syncthreads();

    // ---- per-class first-15 stats; wave w owns class w ----
    {
        const int c = wave;
        float S = 0.0f;
        float M = -INFINITY;
        int taken = 0;   // selected so far (capped at KT)
        int total = 0;   // full class count
        for (int j = 0; j < 8; ++j) {
            const int pos = j * 64 + lane;
            const bool pred = (s_lab[pos] == c);
            const unsigned long long mask = __ballot(pred);
            const int cnt  = __popcll(mask);
            const int rank = __popcll(mask & ((1ull << lane) - 1ull));
            const bool sel = pred && (taken + rank < KT);
            float vs = sel ? s_dist[pos] : 0.0f;
            float vm = sel ? s_dist[pos] : -INFINITY;
            #pragma unroll
            for (int m = 1; m < 64; m <<= 1) {
                vs += __shfl_xor(vs, m);
                vm = fmaxf(vm, __shfl_xor(vm, m));
            }
            S += vs;
            M = fmaxf(M, vm);
            total += cnt;
            taken += cnt;
            if (taken > KT) taken = KT;
        }
        // Rare: fewer than 15 same-class members -> top_k fills with the
        // lowest-index different-class entries (all tied at -inf).
        if (total < KT) {
            const int need = KT - total;
            int t2 = 0;
            for (int j = 0; j < 8 && t2 < need; ++j) {
                const int pos = j * 64 + lane;
                const bool pred = (s_lab[pos] != c);
                const unsigned long long mask = __ballot(pred);
                const int cnt  = __popcll(mask);
                const int rank = __popcll(mask & ((1ull << lane) - 1ull));
                const bool sel = pred && (t2 + rank < need);
                float vs = sel ? s_dist[pos] : 0.0f;
                float vm = sel ? s_dist[pos] : -INFINITY;
                #pragma unroll
                for (int m = 1; m < 64; m <<= 1) {
                    vs += __shfl_xor(vs, m);
                    vm = fmaxf(vm, __shfl_xor(vm, m));
                }
                S += vs;
                M = fmaxf(M, vm);
                t2 += cnt;
                if (t2 > need) t2 = need;
            }
        }
        if (lane == 0) {
            s_S[c]   = S;
            s_M[c]   = M;
            s_cnt[c] = total;
        }
    }
    __syncthreads();

    // ---- combine classes (8 entries) ----
    if (tid == 0) {
        float margin = -INFINITY;
        float pull = 0.0f;
        for (int c = 0; c < NCLS; ++c) {
            if (s_cnt[c] > 0) margin = fmaxf(margin, s_M[c]);
            pull += (float)s_cnt[c] * s_S[c];
            s_hb[c] = 1.0f + s_M[c];
            s_dc[c] = (float)(P - s_cnt[c]);
        }
        s_margin = 1.0f + margin;
        s_pull = pull;
    }
    __syncthreads();

    // ---- push term; one point per thread ----
    {
        const float dv = s_dist[tid];
        const int   c  = s_lab[tid];
        const float h  = fmaxf(s_hb[c] - dv, 0.0f);
        float v = (dv < s_margin) ? s_dc[c] * h : 0.0f;
        #pragma unroll
        for (int m = 1; m < 64; m <<= 1) v += __shfl_xor(v, m);
        if (lane == 0) s_wsum[wave] = v;
    }
    __syncthreads();

    if (tid == 0) {
        float t = s_pull;
        #pragma unroll
        for (int w = 0; w < 8; ++w) t += s_wsum[w];
        atomicAdd(out, t * (1.0f / ((float)NSEG * (float)P)));
    }
}

extern "C" void kernel_launch(void* const* d_in, const int* in_sizes, int n_in,
                              void* d_out, int out_size, void* d_ws, size_t ws_size,
                              hipStream_t stream) {
    const float* center  = (const float*)d_in[0];  // (128, 64)
    const float* outputs = (const float*)d_in[1];  // (128, 512, 64)
    const int*   labels  = (const int*)d_in[2];    // (128, 512)
    float* out  = (float*)d_out;
    float* dist = (float*)d_ws;                    // 128*512 floats = 256 KB

    dist_kernel<<<dim3(NSEG * 4), dim3(256), 0, stream>>>(center, outputs, dist, out);
    combine_kernel<<<dim3(NSEG), dim3(512), 0, stream>>>(dist, labels, out);
}